// Round 14
// baseline (195.413 us; speedup 1.0000x reference)
//
#include <hip/hip_runtime.h>
#include <math.h>

#define DPI 3.141592653589793238462643383279502884

// ---------------- device helpers ----------------
__device__ __forceinline__ float wave_sum64(float v) {
#pragma unroll
  for (int off = 32; off > 0; off >>= 1) v += __shfl_xor(v, off, 64);
  return v;
}

__device__ __forceinline__ float gelu_tanh(float v) {
  float u = 0.7978845608028654f * (v + 0.044715f * v * v * v);
  return 0.5f * v * (1.0f + tanhf(u));
}

#define CN255F ((float)(-2.0 * DPI / 255.0))
#define CN127F ((float)(2.0 * DPI / 127.0))
#define PIO255F ((float)(DPI / 255.0))

// ======================= ct_pre: full-K dft + all setup, one launch =======================
// blocks 0..127   : forward DFT (t=vb), K=255 full, half-spectrum m=0..63
// blocks 128..382 : Wigner tables;  383..446 : A2;  447..510 : Mm/bias2;  511 : tv
// ftm layout: [t][mi][c], mi = m in [0,64)  (x real => ftm(-m)=conj(ftm(m)))

__device__ __forceinline__ void dft_block(int t, int tid, const float* __restrict__ x,
                                          float* __restrict__ ftm_re, float* __restrict__ ftm_im,
                                          char* sm) {
  float* xs_ = (float*)sm;  // [64][64] 16 KB
  int cg_ = tid & 15, mg = tid >> 4;
  float wr[4], wi[4], rc[4], rs[4];
#pragma unroll
  for (int j = 0; j < 4; ++j) {
    int m = mg * 4 + j;
    __sincosf(CN255F * (float)m, &rs[j], &rc[j]);
    wr[j] = 1.0f; wi[j] = 0.0f;  // p starts at 0
  }
  float accr[4][4], acci[4][4];
#pragma unroll
  for (int j = 0; j < 4; ++j)
#pragma unroll
    for (int q = 0; q < 4; ++q) { accr[j][q] = 0.f; acci[j][q] = 0.f; }
  for (int k0 = 0; k0 < 255; k0 += 64) {
    int kn = (255 - k0 < 64) ? 255 - k0 : 64;
    __syncthreads();
    {
      const float4* src = (const float4*)(x + ((size_t)t * 255 + k0) * 64);
      float4* dst = (float4*)xs_;
      int lim = kn * 16;
#pragma unroll
      for (int q = 0; q < 4; ++q) {
        int fidx = tid + q * 256;
        if (fidx < lim) dst[fidx] = src[fidx];
      }
    }
    __syncthreads();
#pragma unroll 2
    for (int k = 0; k < kn; ++k) {
      float4 xv = *(const float4*)&xs_[k * 64 + cg_ * 4];
      float xv4[4] = {xv.x, xv.y, xv.z, xv.w};
#pragma unroll
      for (int j = 0; j < 4; ++j) {
#pragma unroll
        for (int q = 0; q < 4; ++q) {
          accr[j][q] = fmaf(xv4[q], wr[j], accr[j][q]);
          acci[j][q] = fmaf(xv4[q], wi[j], acci[j][q]);
        }
        float nw = wr[j] * rc[j] - wi[j] * rs[j];
        wi[j] = fmaf(wr[j], rs[j], wi[j] * rc[j]);
        wr[j] = nw;
      }
    }
  }
#pragma unroll
  for (int j = 0; j < 4; ++j) {
    int mi = mg * 4 + j;
    size_t ob = ((size_t)t * 64 + mi) * 64 + cg_ * 4;
    *(float4*)(ftm_re + ob) = make_float4(accr[j][0], accr[j][1], accr[j][2], accr[j][3]);
    *(float4*)(ftm_im + ob) = make_float4(acci[j][0], acci[j][1], acci[j][2], acci[j][3]);
  }
}

__device__ __forceinline__ void wigner_block(int wb, int tid, float* __restrict__ Deff,
                                             float* __restrict__ Dinv, char* sm) {
  float* LF = (float*)sm;             // [128] log(n!)
  float* red = (float*)(sm + 512);    // [64]
  float* clf = (float*)(sm + 1024);   // [64]
  int mode = (wb < 128) ? 0 : 1;
  int t, mm;
  if (mode == 0) { t = wb; mm = tid; }
  else { mm = wb - 128; t = (tid < 64) ? tid : 63; }
  if (tid < 64) clf[tid] = (float)(-sqrt((2.0 * tid + 1.0) / (4.0 * DPI)));
  if (tid < 128) LF[tid] = (tid == 0) ? 0.f : logf((float)tid);
  __syncthreads();
  for (int s = 1; s < 128; s <<= 1) {
    float add = (tid < 128 && tid >= s) ? LF[tid - s] : 0.f;
    __syncthreads();
    if (tid < 128) LF[tid] += add;
    __syncthreads();
  }
  float coeff = 1.0f;
  int odd = 2 * t + 1;
  if (mode == 0) {
    // quad-weight pair sum, lane-parallel, fp32 with exact int angle reduction (no log -> safe)
    if (tid < 63) {
      int k = 2 * (tid + 1);
      int e = (k * odd) % 510;
      float ang = (float)e * PIO255F;
      red[tid] = 8.0f * __cosf(ang) / (1.0f - (float)(k * k));
    } else if (tid == 63) {
      red[63] = 4.0f;
    }
    __syncthreads();
    for (int s = 32; s > 0; s >>= 1) {
      if (tid < s) red[tid] += red[tid + s];
      __syncthreads();
    }
    float s = red[0] / 255.0f;
    if (t == 127) s *= 0.5f;
    coeff = s * (float)(2.0 * DPI / 255.0);
  }
  bool active = (mode == 0) ? (tid < 127) : (tid < 64);
  if (!active) return;
  int m = mm - 63;
  // half-angle + cos(beta) MUST be double: at beta=pi, cos(beta/2) in fp32 can go
  // negative -> logf(<0)=NaN (round-13 failure). Double gives +6.1e-17 -> finite log.
  double denomN = (mode == 0) ? 255.0 : 127.0;
  double beta = (double)odd * DPI / denomN;
  double chd, shd;
  sincos(0.5 * beta, &shd, &chd);
  float cbf = (float)cos(beta);
  float chf = (float)chd, shf = (float)shd;
  int am = (m < 0) ? -m : m;
  int l0v = (am > 1) ? am : 1;
  float seed;
  if (m == 0) {
    seed = -1.4142135623730951f * shf * chf;
  } else {
    int j = am;
    float lch = logf(chf), lsh = logf(shf);
    float e0 = 0.5f * (LF[2 * j] - LF[j - 1] - LF[j + 1]);
    float expo = (m >= 1) ? e0 + (float)(j - 1) * lch + (float)(j + 1) * lsh
                          : e0 + (float)(j + 1) * lch + (float)(j - 1) * lsh;
    float sv = __expf(expo);
    seed = (m >= 1 && ((m + 1) & 1)) ? -sv : sv;
  }
  float dl = seed, dm1 = 0.0f, S_cur = 0.0f;
  float mf = (float)m;
  for (int l = 0; l < 64; ++l) {
    float val = 0.0f;
    if (l >= l0v) {
      val = dl * coeff * clf[l];
      float Ld = (float)l, lp = Ld + 1.0f;
      float S_next = sqrtf((lp * lp - mf * mf) * (lp * lp - 1.0f));
      float num1 = (2.0f * Ld + 1.0f) * (Ld * lp * cbf + mf);
      float dn = (num1 * dl - lp * S_cur * dm1) / (Ld * S_next);
      dm1 = dl; dl = dn; S_cur = S_next;
    }
    if (mode == 0) Deff[((size_t)t * 127 + mm) * 64 + l] = val;
    else Dinv[((size_t)mm * 64 + l) * 64 + t] = val;
  }
}

__device__ __forceinline__ void a2_block(int l, int tid, const float* __restrict__ temb,
                                         const float* __restrict__ trw, const float* __restrict__ trb,
                                         const float* __restrict__ tiw, const float* __restrict__ tib,
                                         const float* __restrict__ scw, const float* __restrict__ swr,
                                         const float* __restrict__ swi, float2* __restrict__ A2,
                                         char* sm) {
  float* fb1 = (float*)sm;
  float* fb2 = (float*)(sm + 1024);
  fb1[tid] = temb[tid] * trw[tid * 64 + l];
  fb2[tid] = temb[tid] * tiw[tid * 64 + l];
  __syncthreads();
  for (int s = 128; s > 0; s >>= 1) {
    if (tid < s) { fb1[tid] += fb1[tid + s]; fb2[tid] += fb2[tid + s]; }
    __syncthreads();
  }
  float tr = fb1[0] + trb[l], ti = fb2[0] + tib[l];
  int o = tid & 63, iq = tid >> 6;
  for (int i = iq * 16; i < iq * 16 + 16; ++i) {
    int idx = (l * 64 + i) * 64 + o;
    float r = swr[idx], s2 = swi[idx];
    A2[idx] = make_float2(scw[i * 64 + o] + tr * r - ti * s2, tr * s2 + ti * r);
  }
}

__device__ __forceinline__ void m_block(int j, int tid, const float* __restrict__ temb,
                                        const float* __restrict__ stw, const float* __restrict__ stb,
                                        const float* __restrict__ c1w, const float* __restrict__ c1b,
                                        const float* __restrict__ sweight, float* __restrict__ Mm,
                                        float* __restrict__ bias2, char* sm) {
  float* fb1 = (float*)sm;
  float* fb2 = (float*)(sm + 1024);
  int o = tid & 63, part = tid >> 6;
  float p = 0.f;
  for (int k = part * 64; k < part * 64 + 64; ++k)
    p = fmaf(temb[k], stw[k * 128 + o], p);
  fb1[part * 64 + o] = p;
  __syncthreads();
  if (part == 0) fb2[o] = fb1[o] + fb1[64 + o] + fb1[128 + o] + fb1[192 + o] + stb[o];
  __syncthreads();
  float tvo = fb2[o];
  float q = 0.f;
  for (int i = part * 16; i < part * 16 + 16; ++i)
    q = fmaf(c1w[j * 64 + i], sweight[i * 64 + o], q);
  __syncthreads();
  fb1[part * 64 + o] = q;
  __syncthreads();
  if (part == 0) Mm[j * 64 + o] = tvo * (fb1[o] + fb1[64 + o] + fb1[128 + o] + fb1[192 + o]);
  if (j == 0) {
    float bq = 0.f;
    for (int i = part * 16; i < part * 16 + 16; ++i)
      bq = fmaf(c1b[i], sweight[i * 64 + o], bq);
    __syncthreads();
    fb1[part * 64 + o] = bq;
    __syncthreads();
    if (part == 0) bias2[o] = tvo * (fb1[o] + fb1[64 + o] + fb1[128 + o] + fb1[192 + o]);
  }
}

__device__ __forceinline__ void tv_block(int tid, const float* __restrict__ temb,
                                         const float* __restrict__ stw, const float* __restrict__ stb,
                                         float* __restrict__ tv, char* sm) {
  float* fb1 = (float*)sm;
  int o = tid & 127, part = tid >> 7;
  float p = 0.f;
  for (int k = part * 128; k < part * 128 + 128; ++k)
    p = fmaf(temb[k], stw[k * 128 + o], p);
  fb1[part * 128 + o] = p;
  __syncthreads();
  if (part == 0) tv[o] = fb1[o] + fb1[128 + o] + stb[o];
}

__global__ __launch_bounds__(256) void ct_pre(
    const float* __restrict__ x, const float* __restrict__ temb,
    const float* __restrict__ trw, const float* __restrict__ trb,
    const float* __restrict__ tiw, const float* __restrict__ tib,
    const float* __restrict__ stw, const float* __restrict__ stb,
    const float* __restrict__ scw, const float* __restrict__ swr,
    const float* __restrict__ swi, const float* __restrict__ c1w,
    const float* __restrict__ c1b, const float* __restrict__ sweight,
    float* __restrict__ Deff, float* __restrict__ Dinv,
    float2* __restrict__ A2, float* __restrict__ Mm,
    float* __restrict__ bias2, float* __restrict__ tv,
    float* __restrict__ ftm_re, float* __restrict__ ftm_im) {
  __shared__ __align__(16) char sm[16384];
  int vb = blockIdx.x;
  int tid = threadIdx.x;
  if (vb < 128) dft_block(vb, tid, x, ftm_re, ftm_im, sm);
  else if (vb < 383) wigner_block(vb - 128, tid, Deff, Dinv, sm);
  else if (vb < 447) a2_block(vb - 383, tid, temb, trw, trb, tiw, tib, scw, swr, swi, A2, sm);
  else if (vb < 511) m_block(vb - 447, tid, temb, stw, stb, c1w, c1b, sweight, Mm, bias2, sm);
  else tv_block(tid, temb, stw, stb, tv, sm);
}

// ---------------- forward projection: full K=128 t, conj-expanded half-spectrum ----------------
// grid (mm=127, lh=2), block 256. flm[mm][l][c] single (no partials).
__global__ __launch_bounds__(256) void ct_projf(const float* __restrict__ Deff,
                                                const float* __restrict__ ftm_re,
                                                const float* __restrict__ ftm_im,
                                                float* __restrict__ flm_re,
                                                float* __restrict__ flm_im) {
  __shared__ float Dsh[64][32];
  __shared__ float fr_[64][64], fi_[64][64];
  int mm = blockIdx.x, lh = blockIdx.y;
  int mi = (mm >= 63) ? (mm - 63) : (63 - mm);
  float csign = (mm >= 63) ? 1.0f : -1.0f;
  int tid = threadIdx.x;
  int cg_ = tid & 15, lg = tid >> 4;
  float ar[2][4], ai[2][4];
#pragma unroll
  for (int li = 0; li < 2; ++li)
#pragma unroll
    for (int q = 0; q < 4; ++q) { ar[li][q] = 0.f; ai[li][q] = 0.f; }
  for (int th2 = 0; th2 < 2; ++th2) {
    int tb = th2 * 64;
    __syncthreads();
    for (int e = tid; e < 64 * 32; e += 256) {
      int r = e >> 5, li = e & 31;
      Dsh[r][li] = Deff[((size_t)(tb + r) * 127 + mm) * 64 + lh * 32 + li];
    }
    for (int e = tid; e < 64 * 64; e += 256) {
      int r = e >> 6, c = e & 63;
      size_t idx = ((size_t)(tb + r) * 64 + mi) * 64 + c;
      fr_[r][c] = ftm_re[idx];
      fi_[r][c] = csign * ftm_im[idx];
    }
    __syncthreads();
#pragma unroll 4
    for (int k = 0; k < 64; ++k) {
      float4 fr4 = *(const float4*)&fr_[k][cg_ * 4];
      float4 fi4 = *(const float4*)&fi_[k][cg_ * 4];
      float2 d2 = *(const float2*)&Dsh[k][lg * 2];
      float frv[4] = {fr4.x, fr4.y, fr4.z, fr4.w};
      float fiv[4] = {fi4.x, fi4.y, fi4.z, fi4.w};
      float dv[2] = {d2.x, d2.y};
#pragma unroll
      for (int li = 0; li < 2; ++li)
#pragma unroll
        for (int q = 0; q < 4; ++q) {
          ar[li][q] = fmaf(dv[li], frv[q], ar[li][q]);
          ai[li][q] = fmaf(dv[li], fiv[q], ai[li][q]);
        }
    }
  }
#pragma unroll
  for (int li = 0; li < 2; ++li) {
    size_t row = ((size_t)mm * 64 + lh * 32 + lg * 2 + li) * 64 + cg_ * 4;
    *(float4*)(flm_re + row) = make_float4(ar[li][0], ar[li][1], ar[li][2], ar[li][3]);
    *(float4*)(flm_im + row) = make_float4(ai[li][0], ai[li][1], ai[li][2], ai[li][3]);
  }
}

// ---------------- fused channel mixes, single flm input ----------------
// grid (l=64, mh=2, oh=2), block 256.
__global__ __launch_bounds__(256) void ct_mix(const float* __restrict__ flm_re,
                                              const float* __restrict__ flm_im,
                                              const float2* __restrict__ A2,
                                              const float* __restrict__ Mm,
                                              const float* __restrict__ scb,
                                              const float* __restrict__ bias2,
                                              const float* __restrict__ Deff,
                                              float* __restrict__ s_re, float* __restrict__ s_im,
                                              float* __restrict__ h_re, float* __restrict__ h_im) {
  __shared__ float Ar_[64][32], Ai_[64][32], Msh[64][32];
  __shared__ float Br_[64][65], Bi_[64][65];
  __shared__ float rb[256];
  int l = blockIdx.x, mh = blockIdx.y, oh = blockIdx.z;
  int tid = threadIdx.x;
  int og = tid & 15, mg = tid >> 4;
  rb[tid] = (mh == 0 && tid < 128) ? Deff[((size_t)tid * 127 + 63) * 64 + l] : 0.f;
  __syncthreads();
  for (int s = 128; s > 0; s >>= 1) {
    if (tid < s) rb[tid] += rb[tid + s];
    __syncthreads();
  }
  float slv = rb[0];
  for (int e = tid; e < 64 * 32; e += 256) {
    int r = e >> 5, oi = e & 31;
    float2 aa = A2[((size_t)l * 64 + r) * 64 + oh * 32 + oi];
    Ar_[r][oi] = aa.x; Ai_[r][oi] = aa.y;
    Msh[r][oi] = Mm[r * 64 + oh * 32 + oi];
  }
  for (int e = tid; e < 64 * 64; e += 256) {
    int mi = e >> 6, i = e & 63;
    int gmm = mh * 64 + mi; if (gmm > 126) gmm = 126;
    size_t idx = ((size_t)gmm * 64 + l) * 64 + i;
    Br_[mi][i] = flm_re[idx];
    Bi_[mi][i] = flm_im[idx];
  }
  __syncthreads();
  int o0 = oh * 32 + og * 2;
  float b0[2] = {scb[o0], scb[o0 + 1]};
  float sr[4][2], si[4][2], hr[4][2], hi[4][2];
#pragma unroll
  for (int jm = 0; jm < 4; ++jm)
#pragma unroll
    for (int qo = 0; qo < 2; ++qo) {
      sr[jm][qo] = b0[qo]; si[jm][qo] = 0.f; hr[jm][qo] = 0.f; hi[jm][qo] = 0.f;
    }
#pragma unroll 4
  for (int k = 0; k < 64; ++k) {
    float2 ar2 = *(const float2*)&Ar_[k][og * 2];
    float2 ai2 = *(const float2*)&Ai_[k][og * 2];
    float2 mv2 = *(const float2*)&Msh[k][og * 2];
    float br4[4], bi4[4];
#pragma unroll
    for (int jm = 0; jm < 4; ++jm) {
      br4[jm] = Br_[mg * 4 + jm][k];
      bi4[jm] = Bi_[mg * 4 + jm][k];
    }
    float arv[2] = {ar2.x, ar2.y}, aiv[2] = {ai2.x, ai2.y}, mvv[2] = {mv2.x, mv2.y};
#pragma unroll
    for (int jm = 0; jm < 4; ++jm)
#pragma unroll
      for (int qo = 0; qo < 2; ++qo) {
        sr[jm][qo] = fmaf(br4[jm], arv[qo], sr[jm][qo]);
        sr[jm][qo] = fmaf(-bi4[jm], aiv[qo], sr[jm][qo]);
        si[jm][qo] = fmaf(br4[jm], aiv[qo], si[jm][qo]);
        si[jm][qo] = fmaf(bi4[jm], arv[qo], si[jm][qo]);
        hr[jm][qo] = fmaf(br4[jm], mvv[qo], hr[jm][qo]);
        hi[jm][qo] = fmaf(bi4[jm], mvv[qo], hi[jm][qo]);
      }
  }
  float bb[2] = {bias2[o0], bias2[o0 + 1]};
#pragma unroll
  for (int jm = 0; jm < 4; ++jm) {
    int gmm = mh * 64 + mg * 4 + jm;
    if (gmm > 126) continue;
    if (gmm == 63) {
#pragma unroll
      for (int qo = 0; qo < 2; ++qo)
        hr[jm][qo] = fmaf(255.0f * slv, bb[qo], hr[jm][qo]);
    }
    size_t row = ((size_t)gmm * 64 + l) * 64 + o0;
    *(float2*)(s_re + row) = make_float2(sr[jm][0], sr[jm][1]);
    *(float2*)(s_im + row) = make_float2(si[jm][0], si[jm][1]);
    *(float2*)(h_re + row) = make_float2(hr[jm][0], hr[jm][1]);
    *(float2*)(h_im + row) = make_float2(hi[jm][0], hi[jm][1]);
  }
}

// ---------------- inverse projection, planar, c-split ----------------
// grid (mm=127, br=2, ch=2), block 256.
__global__ __launch_bounds__(256) void ct_proji(const float* __restrict__ Dinv,
                                                const float* __restrict__ s_re,
                                                const float* __restrict__ s_im,
                                                const float* __restrict__ h_re,
                                                const float* __restrict__ h_im,
                                                float* __restrict__ fos_re, float* __restrict__ fos_im,
                                                float* __restrict__ foh_re, float* __restrict__ foh_im) {
  __shared__ float Dsh[64][64];
  __shared__ float Br_[64][32], Bi_[64][32];
  int mm = blockIdx.x, br = blockIdx.y, ch = blockIdx.z;
  const float* ire = br ? h_re : s_re;
  const float* iim = br ? h_im : s_im;
  float* ore = br ? foh_re : fos_re;
  float* oim = br ? foh_im : fos_im;
  int tid = threadIdx.x;
  int cg_ = tid & 15, tg = tid >> 4;
  for (int e = tid; e < 64 * 64; e += 256) {
    int r = e >> 6, tt = e & 63;
    Dsh[r][tt] = Dinv[((size_t)mm * 64 + r) * 64 + tt];
  }
  for (int e = tid; e < 64 * 32; e += 256) {
    int r = e >> 5, cc = e & 31;
    size_t idx = ((size_t)mm * 64 + r) * 64 + ch * 32 + cc;
    Br_[r][cc] = ire[idx];
    Bi_[r][cc] = iim[idx];
  }
  __syncthreads();
  float ar[4][2], ai[4][2];
#pragma unroll
  for (int j = 0; j < 4; ++j)
#pragma unroll
    for (int q = 0; q < 2; ++q) { ar[j][q] = 0.f; ai[j][q] = 0.f; }
#pragma unroll 4
  for (int k = 0; k < 64; ++k) {
    float4 d4 = *(const float4*)&Dsh[k][tg * 4];
    float2 fr2 = *(const float2*)&Br_[k][cg_ * 2];
    float2 fi2 = *(const float2*)&Bi_[k][cg_ * 2];
    float dv[4] = {d4.x, d4.y, d4.z, d4.w};
    float frv[2] = {fr2.x, fr2.y}, fiv[2] = {fi2.x, fi2.y};
#pragma unroll
    for (int j = 0; j < 4; ++j)
#pragma unroll
      for (int q = 0; q < 2; ++q) {
        ar[j][q] = fmaf(dv[j], frv[q], ar[j][q]);
        ai[j][q] = fmaf(dv[j], fiv[q], ai[j][q]);
      }
  }
#pragma unroll
  for (int j = 0; j < 4; ++j) {
    int t = tg * 4 + j;
    size_t ob = ((size_t)t * 127 + mm) * 64 + ch * 32 + cg_ * 2;
    *(float2*)(ore + ob) = make_float2(ar[j][0], ar[j][1]);
    *(float2*)(oim + ob) = make_float2(ai[j][0], ai[j][1]);
  }
}

// ---------------- inverse DFT: full K=127, register twiddles ----------------
// grid (t=64, br=2, ph=2), block 256. Direct outputs (no partials).
__global__ __launch_bounds__(256) void ct_idft(const float* __restrict__ fos_re,
                                               const float* __restrict__ fos_im,
                                               const float* __restrict__ foh_re,
                                               const float* __restrict__ foh_im,
                                               float* __restrict__ xsb, float* __restrict__ hsb) {
  __shared__ float Br_[32][64], Bi_[32][64];  // 16 KB
  int t = blockIdx.x, br = blockIdx.y, ph = blockIdx.z;
  const float* fre = br ? foh_re : fos_re;
  const float* fim = br ? foh_im : fos_im;
  float* outp = br ? hsb : xsb;
  int tid = threadIdx.x;
  int cg_ = tid & 15, pg = tid >> 4;
  float wc[4], ws[4], rc[4], rs[4];
#pragma unroll
  for (int j = 0; j < 4; ++j) {
    int gp = ph * 64 + pg * 4 + j; if (gp > 126) gp = 126;
    __sincosf(CN127F * (float)gp, &rs[j], &rc[j]);
    int r0 = (-63 * gp) % 127;  // k starts at mm=0 -> m=-63 (angle class exact mod 2pi)
    __sincosf(CN127F * (float)r0, &ws[j], &wc[j]);
  }
  float acc[4][4];
#pragma unroll
  for (int j = 0; j < 4; ++j)
#pragma unroll
    for (int q = 0; q < 4; ++q) acc[j][q] = 0.f;
  for (int k0 = 0; k0 < 127; k0 += 32) {
    int kn = (127 - k0 < 32) ? 127 - k0 : 32;
    __syncthreads();
    for (int e = tid; e < 32 * 64; e += 256) {
      int r = e >> 6, j = e & 63;
      if (r < kn) {
        size_t bidx = ((size_t)t * 127 + k0 + r) * 64 + j;
        Br_[r][j] = fre[bidx]; Bi_[r][j] = fim[bidx];
      }
    }
    __syncthreads();
#pragma unroll 2
    for (int k = 0; k < kn; ++k) {
      float4 b_r = *(const float4*)&Br_[k][cg_ * 4];
      float4 b_i = *(const float4*)&Bi_[k][cg_ * 4];
      float brv[4] = {b_r.x, b_r.y, b_r.z, b_r.w};
      float biv[4] = {b_i.x, b_i.y, b_i.z, b_i.w};
#pragma unroll
      for (int j = 0; j < 4; ++j) {
#pragma unroll
        for (int q = 0; q < 4; ++q) {
          acc[j][q] = fmaf(brv[q], wc[j], acc[j][q]);
          acc[j][q] = fmaf(biv[q], -ws[j], acc[j][q]);
        }
        float nw = wc[j] * rc[j] - ws[j] * rs[j];
        ws[j] = fmaf(wc[j], rs[j], ws[j] * rc[j]);
        wc[j] = nw;
      }
    }
  }
#pragma unroll
  for (int j = 0; j < 4; ++j) {
    int gp = ph * 64 + pg * 4 + j;
    if (gp > 126) continue;
    *(float4*)(outp + ((size_t)t * 127 + gp) * 64 + cg_ * 4) =
        make_float4(acc[j][0], acc[j][1], acc[j][2], acc[j][3]);
  }
}

// ---------------- epilogue: one wave per row ----------------
// grid 2032, block 256 (4 waves).
__global__ __launch_bounds__(256) void ct_fin(const float* __restrict__ xsb,
                                              const float* __restrict__ hsb,
                                              const float* __restrict__ c2w,
                                              const float* __restrict__ c2b,
                                              const float* __restrict__ tv,
                                              const float* __restrict__ lns,
                                              const float* __restrict__ lnb,
                                              float* __restrict__ out) {
  int w = threadIdx.x >> 6, lane = threadIdx.x & 63;
  size_t row = (size_t)blockIdx.x * 4 + w;  // < 8128
  size_t base = row * 64 + lane;
  float hv = hsb[base];
  float xv = xsb[base];
  float acc = c2b[lane] + tv[64 + lane];
#pragma unroll 16
  for (int i = 0; i < 64; ++i)
    acc = fmaf(__shfl(hv, i, 64), c2w[i * 64 + lane], acc);
  float ss = wave_sum64(xv * xv);
  xv = xv / (sqrtf(ss) + 1e-6f);
  float y = xv + acc;
  float g = gelu_tanh(y);
  float mu = wave_sum64(g) * (1.0f / 64.0f);
  float d = g - mu;
  float var = wave_sum64(d * d) * (1.0f / 64.0f);
  out[base] = d * rsqrtf(var + 1e-6f) * lns[lane] + lnb[lane];
}

// ---------------- host launcher ----------------
extern "C" void kernel_launch(void* const* d_in, const int* in_sizes, int n_in,
                              void* d_out, int out_size, void* d_ws, size_t ws_size,
                              hipStream_t stream) {
  const float* x = (const float*)d_in[0];
  const float* temb = (const float*)d_in[1];
  const float* scw = (const float*)d_in[2];
  const float* scb = (const float*)d_in[3];
  const float* swr = (const float*)d_in[4];
  const float* swi = (const float*)d_in[5];
  const float* strw = (const float*)d_in[6];
  const float* strb = (const float*)d_in[7];
  const float* stiw = (const float*)d_in[8];
  const float* stib = (const float*)d_in[9];
  const float* c1w = (const float*)d_in[10];
  const float* c1b = (const float*)d_in[11];
  const float* stw = (const float*)d_in[12];
  const float* stb = (const float*)d_in[13];
  const float* sweight = (const float*)d_in[14];
  const float* c2w = (const float*)d_in[15];
  const float* c2b = (const float*)d_in[16];
  const float* lns = (const float*)d_in[17];
  const float* lnb = (const float*)d_in[18];
  float* out = (float*)d_out;

  char* base = (char*)d_ws;
  size_t off = 0;
  auto alloc = [&](size_t bytes) -> void* {
    void* p = base + off;
    off += (bytes + 255) & ~(size_t)255;
    return p;
  };
  float* tv = (float*)alloc(128 * sizeof(float));
  float* Mm = (float*)alloc(4096 * sizeof(float));
  float* bias2 = (float*)alloc(64 * sizeof(float));
  float2* A2 = (float2*)alloc(262144 * sizeof(float2));
  float* Deff = (float*)alloc(1040384 * sizeof(float));   // [t<128][mm][l]
  float* Dinv = (float*)alloc(520192 * sizeof(float));    // [mm][l][t<64]
  float* ftm_re = (float*)alloc(524288 * sizeof(float));  // [t<128][mi<64][c]
  float* ftm_im = (float*)alloc(524288 * sizeof(float));
  float* flm_re = (float*)alloc(520192 * sizeof(float));  // [mm][l][c]
  float* flm_im = (float*)alloc(520192 * sizeof(float));
  float* s_re = (float*)alloc(520192 * sizeof(float));
  float* s_im = (float*)alloc(520192 * sizeof(float));
  float* h_re = (float*)alloc(520192 * sizeof(float));
  float* h_im = (float*)alloc(520192 * sizeof(float));
  float* fos_re = (float*)alloc(520192 * sizeof(float));  // [t<64][mm][c]
  float* fos_im = (float*)alloc(520192 * sizeof(float));
  float* foh_re = (float*)alloc(520192 * sizeof(float));
  float* foh_im = (float*)alloc(520192 * sizeof(float));
  float* xsb = (float*)alloc(520192 * sizeof(float));
  float* hsb = (float*)alloc(520192 * sizeof(float));
  if (off > ws_size) return;  // workspace too small -> visible failure

  hipLaunchKernelGGL(ct_pre, dim3(512), dim3(256), 0, stream,
                     x, temb, strw, strb, stiw, stib, stw, stb,
                     scw, swr, swi, c1w, c1b, sweight,
                     Deff, Dinv, A2, Mm, bias2, tv, ftm_re, ftm_im);
  hipLaunchKernelGGL(ct_projf, dim3(127, 2), dim3(256), 0, stream, Deff,
                     ftm_re, ftm_im, flm_re, flm_im);
  hipLaunchKernelGGL(ct_mix, dim3(64, 2, 2), dim3(256), 0, stream,
                     flm_re, flm_im, A2, Mm, scb, bias2, Deff,
                     s_re, s_im, h_re, h_im);
  hipLaunchKernelGGL(ct_proji, dim3(127, 2, 2), dim3(256), 0, stream, Dinv,
                     s_re, s_im, h_re, h_im, fos_re, fos_im, foh_re, foh_im);
  hipLaunchKernelGGL(ct_idft, dim3(64, 2, 2), dim3(256), 0, stream,
                     fos_re, fos_im, foh_re, foh_im, xsb, hsb);
  hipLaunchKernelGGL(ct_fin, dim3(2032), dim3(256), 0, stream, xsb, hsb,
                     c2w, c2b, tv, lns, lnb, out);
}

// Round 15
// 194.701 us; speedup vs baseline: 1.0037x; 1.0037x over previous
//
#include <hip/hip_runtime.h>
#include <math.h>

#define DPI 3.141592653589793238462643383279502884

// ---------------- device helpers ----------------
__device__ __forceinline__ float wave_sum64(float v) {
#pragma unroll
  for (int off = 32; off > 0; off >>= 1) v += __shfl_xor(v, off, 64);
  return v;
}

__device__ __forceinline__ float gelu_tanh(float v) {
  float u = 0.7978845608028654f * (v + 0.044715f * v * v * v);
  return 0.5f * v * (1.0f + tanhf(u));
}

#define CN255F ((float)(-2.0 * DPI / 255.0))
#define CN127F ((float)(2.0 * DPI / 127.0))
#define PIO255F ((float)(DPI / 255.0))

// ======================= ct_pre: dft (c-split, prefetched) + all setup =======================
// blocks 0..255   : forward DFT (t=vb>>1, ch=vb&1), K=255 full, half-spectrum m=0..63
// blocks 256..510 : Wigner tables;  511..574 : A2;  575..638 : Mm/bias2;  639 : tv
// ftm layout: [t][mi][c], mi = m in [0,64)  (x real => ftm(-m)=conj(ftm(m)))

__device__ __forceinline__ void dft_block(int idx, int tid, const float* __restrict__ x,
                                          float* __restrict__ ftm_re, float* __restrict__ ftm_im,
                                          char* sm) {
  float* xs_ = (float*)sm;  // [64][32] 8 KB
  int t = idx >> 1, ch = idx & 1;
  int cbase = ch * 32;
  int cg_ = tid & 7, mg = tid >> 3;  // mg in [0,32), 2 m per thread
  float wr[2], wi[2], rc[2], rs[2];
#pragma unroll
  for (int j = 0; j < 2; ++j) {
    int m = mg * 2 + j;
    __sincosf(CN255F * (float)m, &rs[j], &rc[j]);
    wr[j] = 1.0f; wi[j] = 0.0f;  // p starts at 0
  }
  float accr[2][4], acci[2][4];
#pragma unroll
  for (int j = 0; j < 2; ++j)
#pragma unroll
    for (int q = 0; q < 4; ++q) { accr[j][q] = 0.f; acci[j][q] = 0.f; }
  for (int k0 = 0; k0 < 255; k0 += 64) {
    int kn = (255 - k0 < 64) ? 255 - k0 : 64;
    __syncthreads();
    {
      int lim = kn * 8;  // float4s in this chunk
      for (int f = tid; f < lim; f += 256) {
        int r = f >> 3, cc = f & 7;
        ((float4*)xs_)[f] =
            *(const float4*)(x + ((size_t)t * 255 + k0 + r) * 64 + cbase + cc * 4);
      }
    }
    __syncthreads();
    // distance-2 register prefetch of LDS reads
    float4 cur = *(const float4*)&xs_[0 * 32 + cg_ * 4];
    float4 nxt = (kn > 1) ? *(const float4*)&xs_[1 * 32 + cg_ * 4] : cur;
    for (int k = 0; k < kn; ++k) {
      float4 nn = (k + 2 < kn) ? *(const float4*)&xs_[(k + 2) * 32 + cg_ * 4] : cur;
      float xv4[4] = {cur.x, cur.y, cur.z, cur.w};
#pragma unroll
      for (int j = 0; j < 2; ++j) {
#pragma unroll
        for (int q = 0; q < 4; ++q) {
          accr[j][q] = fmaf(xv4[q], wr[j], accr[j][q]);
          acci[j][q] = fmaf(xv4[q], wi[j], acci[j][q]);
        }
        float nw = wr[j] * rc[j] - wi[j] * rs[j];
        wi[j] = fmaf(wr[j], rs[j], wi[j] * rc[j]);
        wr[j] = nw;
      }
      cur = nxt; nxt = nn;
    }
  }
#pragma unroll
  for (int j = 0; j < 2; ++j) {
    int mi = mg * 2 + j;
    size_t ob = ((size_t)t * 64 + mi) * 64 + cbase + cg_ * 4;
    *(float4*)(ftm_re + ob) = make_float4(accr[j][0], accr[j][1], accr[j][2], accr[j][3]);
    *(float4*)(ftm_im + ob) = make_float4(acci[j][0], acci[j][1], acci[j][2], acci[j][3]);
  }
}

__device__ __forceinline__ void wigner_block(int wb, int tid, float* __restrict__ Deff,
                                             float* __restrict__ Dinv, char* sm) {
  float* LF = (float*)sm;             // [128] log(n!)
  float* red = (float*)(sm + 512);    // [64]
  float* clf = (float*)(sm + 1024);   // [64]
  int mode = (wb < 128) ? 0 : 1;
  int t, mm;
  if (mode == 0) { t = wb; mm = tid; }
  else { mm = wb - 128; t = (tid < 64) ? tid : 63; }
  if (tid < 64) clf[tid] = (float)(-sqrt((2.0 * tid + 1.0) / (4.0 * DPI)));
  if (tid < 128) LF[tid] = (tid == 0) ? 0.f : logf((float)tid);
  __syncthreads();
  for (int s = 1; s < 128; s <<= 1) {
    float add = (tid < 128 && tid >= s) ? LF[tid - s] : 0.f;
    __syncthreads();
    if (tid < 128) LF[tid] += add;
    __syncthreads();
  }
  float coeff = 1.0f;
  int odd = 2 * t + 1;
  if (mode == 0) {
    if (tid < 63) {
      int k = 2 * (tid + 1);
      int e = (k * odd) % 510;
      float ang = (float)e * PIO255F;
      red[tid] = 8.0f * __cosf(ang) / (1.0f - (float)(k * k));
    } else if (tid == 63) {
      red[63] = 4.0f;
    }
    __syncthreads();
    for (int s = 32; s > 0; s >>= 1) {
      if (tid < s) red[tid] += red[tid + s];
      __syncthreads();
    }
    float s = red[0] / 255.0f;
    if (t == 127) s *= 0.5f;
    coeff = s * (float)(2.0 * DPI / 255.0);
  }
  bool active = (mode == 0) ? (tid < 127) : (tid < 64);
  if (!active) return;
  int m = mm - 63;
  // half-angle + cos(beta) in double: at beta=pi, fp32 cos(beta/2) can go negative
  // -> logf(<0)=NaN (round-13 failure). Double gives +6.1e-17 -> finite log.
  double denomN = (mode == 0) ? 255.0 : 127.0;
  double beta = (double)odd * DPI / denomN;
  double chd, shd;
  sincos(0.5 * beta, &shd, &chd);
  float cbf = (float)cos(beta);
  float chf = (float)chd, shf = (float)shd;
  int am = (m < 0) ? -m : m;
  int l0v = (am > 1) ? am : 1;
  float seed;
  if (m == 0) {
    seed = -1.4142135623730951f * shf * chf;
  } else {
    int j = am;
    float lch = logf(chf), lsh = logf(shf);
    float e0 = 0.5f * (LF[2 * j] - LF[j - 1] - LF[j + 1]);
    float expo = (m >= 1) ? e0 + (float)(j - 1) * lch + (float)(j + 1) * lsh
                          : e0 + (float)(j + 1) * lch + (float)(j - 1) * lsh;
    float sv = __expf(expo);
    seed = (m >= 1 && ((m + 1) & 1)) ? -sv : sv;
  }
  float dl = seed, dm1 = 0.0f, S_cur = 0.0f;
  float mf = (float)m;
  for (int l = 0; l < 64; ++l) {
    float val = 0.0f;
    if (l >= l0v) {
      val = dl * coeff * clf[l];
      float Ld = (float)l, lp = Ld + 1.0f;
      float S_next = sqrtf((lp * lp - mf * mf) * (lp * lp - 1.0f));
      float num1 = (2.0f * Ld + 1.0f) * (Ld * lp * cbf + mf);
      float dn = (num1 * dl - lp * S_cur * dm1) / (Ld * S_next);
      dm1 = dl; dl = dn; S_cur = S_next;
    }
    if (mode == 0) Deff[((size_t)t * 127 + mm) * 64 + l] = val;
    else Dinv[((size_t)mm * 64 + l) * 64 + t] = val;
  }
}

__device__ __forceinline__ void a2_block(int l, int tid, const float* __restrict__ temb,
                                         const float* __restrict__ trw, const float* __restrict__ trb,
                                         const float* __restrict__ tiw, const float* __restrict__ tib,
                                         const float* __restrict__ scw, const float* __restrict__ swr,
                                         const float* __restrict__ swi, float2* __restrict__ A2,
                                         char* sm) {
  float* fb1 = (float*)sm;
  float* fb2 = (float*)(sm + 1024);
  fb1[tid] = temb[tid] * trw[tid * 64 + l];
  fb2[tid] = temb[tid] * tiw[tid * 64 + l];
  __syncthreads();
  for (int s = 128; s > 0; s >>= 1) {
    if (tid < s) { fb1[tid] += fb1[tid + s]; fb2[tid] += fb2[tid + s]; }
    __syncthreads();
  }
  float tr = fb1[0] + trb[l], ti = fb2[0] + tib[l];
  int o = tid & 63, iq = tid >> 6;
  for (int i = iq * 16; i < iq * 16 + 16; ++i) {
    int idx = (l * 64 + i) * 64 + o;
    float r = swr[idx], s2 = swi[idx];
    A2[idx] = make_float2(scw[i * 64 + o] + tr * r - ti * s2, tr * s2 + ti * r);
  }
}

__device__ __forceinline__ void m_block(int j, int tid, const float* __restrict__ temb,
                                        const float* __restrict__ stw, const float* __restrict__ stb,
                                        const float* __restrict__ c1w, const float* __restrict__ c1b,
                                        const float* __restrict__ sweight, float* __restrict__ Mm,
                                        float* __restrict__ bias2, char* sm) {
  float* fb1 = (float*)sm;
  float* fb2 = (float*)(sm + 1024);
  int o = tid & 63, part = tid >> 6;
  float p = 0.f;
  for (int k = part * 64; k < part * 64 + 64; ++k)
    p = fmaf(temb[k], stw[k * 128 + o], p);
  fb1[part * 64 + o] = p;
  __syncthreads();
  if (part == 0) fb2[o] = fb1[o] + fb1[64 + o] + fb1[128 + o] + fb1[192 + o] + stb[o];
  __syncthreads();
  float tvo = fb2[o];
  float q = 0.f;
  for (int i = part * 16; i < part * 16 + 16; ++i)
    q = fmaf(c1w[j * 64 + i], sweight[i * 64 + o], q);
  __syncthreads();
  fb1[part * 64 + o] = q;
  __syncthreads();
  if (part == 0) Mm[j * 64 + o] = tvo * (fb1[o] + fb1[64 + o] + fb1[128 + o] + fb1[192 + o]);
  if (j == 0) {
    float bq = 0.f;
    for (int i = part * 16; i < part * 16 + 16; ++i)
      bq = fmaf(c1b[i], sweight[i * 64 + o], bq);
    __syncthreads();
    fb1[part * 64 + o] = bq;
    __syncthreads();
    if (part == 0) bias2[o] = tvo * (fb1[o] + fb1[64 + o] + fb1[128 + o] + fb1[192 + o]);
  }
}

__device__ __forceinline__ void tv_block(int tid, const float* __restrict__ temb,
                                         const float* __restrict__ stw, const float* __restrict__ stb,
                                         float* __restrict__ tv, char* sm) {
  float* fb1 = (float*)sm;
  int o = tid & 127, part = tid >> 7;
  float p = 0.f;
  for (int k = part * 128; k < part * 128 + 128; ++k)
    p = fmaf(temb[k], stw[k * 128 + o], p);
  fb1[part * 128 + o] = p;
  __syncthreads();
  if (part == 0) tv[o] = fb1[o] + fb1[128 + o] + stb[o];
}

__global__ __launch_bounds__(256) void ct_pre(
    const float* __restrict__ x, const float* __restrict__ temb,
    const float* __restrict__ trw, const float* __restrict__ trb,
    const float* __restrict__ tiw, const float* __restrict__ tib,
    const float* __restrict__ stw, const float* __restrict__ stb,
    const float* __restrict__ scw, const float* __restrict__ swr,
    const float* __restrict__ swi, const float* __restrict__ c1w,
    const float* __restrict__ c1b, const float* __restrict__ sweight,
    float* __restrict__ Deff, float* __restrict__ Dinv,
    float2* __restrict__ A2, float* __restrict__ Mm,
    float* __restrict__ bias2, float* __restrict__ tv,
    float* __restrict__ ftm_re, float* __restrict__ ftm_im) {
  __shared__ __align__(16) char sm[16384];
  int vb = blockIdx.x;
  int tid = threadIdx.x;
  if (vb < 256) dft_block(vb, tid, x, ftm_re, ftm_im, sm);
  else if (vb < 511) wigner_block(vb - 256, tid, Deff, Dinv, sm);
  else if (vb < 575) a2_block(vb - 511, tid, temb, trw, trb, tiw, tib, scw, swr, swi, A2, sm);
  else if (vb < 639) m_block(vb - 575, tid, temb, stw, stb, c1w, c1b, sweight, Mm, bias2, sm);
  else tv_block(tid, temb, stw, stb, tv, sm);
}

// ---------------- forward projection: full K=128 t, conj-expanded, prefetched ----------------
// grid (mm=127, lh=2), block 256.
__global__ __launch_bounds__(256) void ct_projf(const float* __restrict__ Deff,
                                                const float* __restrict__ ftm_re,
                                                const float* __restrict__ ftm_im,
                                                float* __restrict__ flm_re,
                                                float* __restrict__ flm_im) {
  __shared__ float Dsh[64][32];
  __shared__ float fr_[64][64], fi_[64][64];
  int mm = blockIdx.x, lh = blockIdx.y;
  int mi = (mm >= 63) ? (mm - 63) : (63 - mm);
  float csign = (mm >= 63) ? 1.0f : -1.0f;
  int tid = threadIdx.x;
  int cg_ = tid & 15, lg = tid >> 4;
  float ar[2][4], ai[2][4];
#pragma unroll
  for (int li = 0; li < 2; ++li)
#pragma unroll
    for (int q = 0; q < 4; ++q) { ar[li][q] = 0.f; ai[li][q] = 0.f; }
  for (int th2 = 0; th2 < 2; ++th2) {
    int tb = th2 * 64;
    __syncthreads();
    for (int e = tid; e < 64 * 32; e += 256) {
      int r = e >> 5, li = e & 31;
      Dsh[r][li] = Deff[((size_t)(tb + r) * 127 + mm) * 64 + lh * 32 + li];
    }
    for (int e = tid; e < 64 * 64; e += 256) {
      int r = e >> 6, c = e & 63;
      size_t idx = ((size_t)(tb + r) * 64 + mi) * 64 + c;
      fr_[r][c] = ftm_re[idx];
      fi_[r][c] = csign * ftm_im[idx];
    }
    __syncthreads();
    float4 cr = *(const float4*)&fr_[0][cg_ * 4];
    float4 ci = *(const float4*)&fi_[0][cg_ * 4];
    float2 cd = *(const float2*)&Dsh[0][lg * 2];
    for (int k = 0; k < 64; ++k) {
      float4 nr = cr, ni = ci;
      float2 nd = cd;
      if (k + 1 < 64) {
        nr = *(const float4*)&fr_[k + 1][cg_ * 4];
        ni = *(const float4*)&fi_[k + 1][cg_ * 4];
        nd = *(const float2*)&Dsh[k + 1][lg * 2];
      }
      float frv[4] = {cr.x, cr.y, cr.z, cr.w};
      float fiv[4] = {ci.x, ci.y, ci.z, ci.w};
      float dv[2] = {cd.x, cd.y};
#pragma unroll
      for (int li = 0; li < 2; ++li)
#pragma unroll
        for (int q = 0; q < 4; ++q) {
          ar[li][q] = fmaf(dv[li], frv[q], ar[li][q]);
          ai[li][q] = fmaf(dv[li], fiv[q], ai[li][q]);
        }
      cr = nr; ci = ni; cd = nd;
    }
  }
#pragma unroll
  for (int li = 0; li < 2; ++li) {
    size_t row = ((size_t)mm * 64 + lh * 32 + lg * 2 + li) * 64 + cg_ * 4;
    *(float4*)(flm_re + row) = make_float4(ar[li][0], ar[li][1], ar[li][2], ar[li][3]);
    *(float4*)(flm_im + row) = make_float4(ai[li][0], ai[li][1], ai[li][2], ai[li][3]);
  }
}

// ---------------- fused channel mixes, single flm input ----------------
// grid (l=64, mh=2, oh=2), block 256.
__global__ __launch_bounds__(256) void ct_mix(const float* __restrict__ flm_re,
                                              const float* __restrict__ flm_im,
                                              const float2* __restrict__ A2,
                                              const float* __restrict__ Mm,
                                              const float* __restrict__ scb,
                                              const float* __restrict__ bias2,
                                              const float* __restrict__ Deff,
                                              float* __restrict__ s_re, float* __restrict__ s_im,
                                              float* __restrict__ h_re, float* __restrict__ h_im) {
  __shared__ float Ar_[64][32], Ai_[64][32], Msh[64][32];
  __shared__ float Br_[64][65], Bi_[64][65];
  __shared__ float rb[256];
  int l = blockIdx.x, mh = blockIdx.y, oh = blockIdx.z;
  int tid = threadIdx.x;
  int og = tid & 15, mg = tid >> 4;
  rb[tid] = (mh == 0 && tid < 128) ? Deff[((size_t)tid * 127 + 63) * 64 + l] : 0.f;
  __syncthreads();
  for (int s = 128; s > 0; s >>= 1) {
    if (tid < s) rb[tid] += rb[tid + s];
    __syncthreads();
  }
  float slv = rb[0];
  for (int e = tid; e < 64 * 32; e += 256) {
    int r = e >> 5, oi = e & 31;
    float2 aa = A2[((size_t)l * 64 + r) * 64 + oh * 32 + oi];
    Ar_[r][oi] = aa.x; Ai_[r][oi] = aa.y;
    Msh[r][oi] = Mm[r * 64 + oh * 32 + oi];
  }
  for (int e = tid; e < 64 * 64; e += 256) {
    int mi = e >> 6, i = e & 63;
    int gmm = mh * 64 + mi; if (gmm > 126) gmm = 126;
    size_t idx = ((size_t)gmm * 64 + l) * 64 + i;
    Br_[mi][i] = flm_re[idx];
    Bi_[mi][i] = flm_im[idx];
  }
  __syncthreads();
  int o0 = oh * 32 + og * 2;
  float b0[2] = {scb[o0], scb[o0 + 1]};
  float sr[4][2], si[4][2], hr[4][2], hi[4][2];
#pragma unroll
  for (int jm = 0; jm < 4; ++jm)
#pragma unroll
    for (int qo = 0; qo < 2; ++qo) {
      sr[jm][qo] = b0[qo]; si[jm][qo] = 0.f; hr[jm][qo] = 0.f; hi[jm][qo] = 0.f;
    }
#pragma unroll 4
  for (int k = 0; k < 64; ++k) {
    float2 ar2 = *(const float2*)&Ar_[k][og * 2];
    float2 ai2 = *(const float2*)&Ai_[k][og * 2];
    float2 mv2 = *(const float2*)&Msh[k][og * 2];
    float br4[4], bi4[4];
#pragma unroll
    for (int jm = 0; jm < 4; ++jm) {
      br4[jm] = Br_[mg * 4 + jm][k];
      bi4[jm] = Bi_[mg * 4 + jm][k];
    }
    float arv[2] = {ar2.x, ar2.y}, aiv[2] = {ai2.x, ai2.y}, mvv[2] = {mv2.x, mv2.y};
#pragma unroll
    for (int jm = 0; jm < 4; ++jm)
#pragma unroll
      for (int qo = 0; qo < 2; ++qo) {
        sr[jm][qo] = fmaf(br4[jm], arv[qo], sr[jm][qo]);
        sr[jm][qo] = fmaf(-bi4[jm], aiv[qo], sr[jm][qo]);
        si[jm][qo] = fmaf(br4[jm], aiv[qo], si[jm][qo]);
        si[jm][qo] = fmaf(bi4[jm], arv[qo], si[jm][qo]);
        hr[jm][qo] = fmaf(br4[jm], mvv[qo], hr[jm][qo]);
        hi[jm][qo] = fmaf(bi4[jm], mvv[qo], hi[jm][qo]);
      }
  }
  float bb[2] = {bias2[o0], bias2[o0 + 1]};
#pragma unroll
  for (int jm = 0; jm < 4; ++jm) {
    int gmm = mh * 64 + mg * 4 + jm;
    if (gmm > 126) continue;
    if (gmm == 63) {
#pragma unroll
      for (int qo = 0; qo < 2; ++qo)
        hr[jm][qo] = fmaf(255.0f * slv, bb[qo], hr[jm][qo]);
    }
    size_t row = ((size_t)gmm * 64 + l) * 64 + o0;
    *(float2*)(s_re + row) = make_float2(sr[jm][0], sr[jm][1]);
    *(float2*)(s_im + row) = make_float2(si[jm][0], si[jm][1]);
    *(float2*)(h_re + row) = make_float2(hr[jm][0], hr[jm][1]);
    *(float2*)(h_im + row) = make_float2(hi[jm][0], hi[jm][1]);
  }
}

// ---------------- inverse projection, planar, c-split, prefetched ----------------
// grid (mm=127, br=2, ch=2), block 256.
__global__ __launch_bounds__(256) void ct_proji(const float* __restrict__ Dinv,
                                                const float* __restrict__ s_re,
                                                const float* __restrict__ s_im,
                                                const float* __restrict__ h_re,
                                                const float* __restrict__ h_im,
                                                float* __restrict__ fos_re, float* __restrict__ fos_im,
                                                float* __restrict__ foh_re, float* __restrict__ foh_im) {
  __shared__ float Dsh[64][64];
  __shared__ float Br_[64][32], Bi_[64][32];
  int mm = blockIdx.x, br = blockIdx.y, ch = blockIdx.z;
  const float* ire = br ? h_re : s_re;
  const float* iim = br ? h_im : s_im;
  float* ore = br ? foh_re : fos_re;
  float* oim = br ? foh_im : fos_im;
  int tid = threadIdx.x;
  int cg_ = tid & 15, tg = tid >> 4;
  for (int e = tid; e < 64 * 64; e += 256) {
    int r = e >> 6, tt = e & 63;
    Dsh[r][tt] = Dinv[((size_t)mm * 64 + r) * 64 + tt];
  }
  for (int e = tid; e < 64 * 32; e += 256) {
    int r = e >> 5, cc = e & 31;
    size_t idx = ((size_t)mm * 64 + r) * 64 + ch * 32 + cc;
    Br_[r][cc] = ire[idx];
    Bi_[r][cc] = iim[idx];
  }
  __syncthreads();
  float ar[4][2], ai[4][2];
#pragma unroll
  for (int j = 0; j < 4; ++j)
#pragma unroll
    for (int q = 0; q < 2; ++q) { ar[j][q] = 0.f; ai[j][q] = 0.f; }
  float4 cd = *(const float4*)&Dsh[0][tg * 4];
  float2 crf = *(const float2*)&Br_[0][cg_ * 2];
  float2 cif = *(const float2*)&Bi_[0][cg_ * 2];
  for (int k = 0; k < 64; ++k) {
    float4 nd = cd; float2 nrf = crf, nif = cif;
    if (k + 1 < 64) {
      nd = *(const float4*)&Dsh[k + 1][tg * 4];
      nrf = *(const float2*)&Br_[k + 1][cg_ * 2];
      nif = *(const float2*)&Bi_[k + 1][cg_ * 2];
    }
    float dv[4] = {cd.x, cd.y, cd.z, cd.w};
    float frv[2] = {crf.x, crf.y}, fiv[2] = {cif.x, cif.y};
#pragma unroll
    for (int j = 0; j < 4; ++j)
#pragma unroll
      for (int q = 0; q < 2; ++q) {
        ar[j][q] = fmaf(dv[j], frv[q], ar[j][q]);
        ai[j][q] = fmaf(dv[j], fiv[q], ai[j][q]);
      }
    cd = nd; crf = nrf; cif = nif;
  }
#pragma unroll
  for (int j = 0; j < 4; ++j) {
    int t = tg * 4 + j;
    size_t ob = ((size_t)t * 127 + mm) * 64 + ch * 32 + cg_ * 2;
    *(float2*)(ore + ob) = make_float2(ar[j][0], ar[j][1]);
    *(float2*)(oim + ob) = make_float2(ai[j][0], ai[j][1]);
  }
}

// ---------------- inverse DFT: full K=127, register twiddles, prefetched ----------------
// grid (t=64, br=2, ph=2), block 256. Direct outputs (no partials).
__global__ __launch_bounds__(256) void ct_idft(const float* __restrict__ fos_re,
                                               const float* __restrict__ fos_im,
                                               const float* __restrict__ foh_re,
                                               const float* __restrict__ foh_im,
                                               float* __restrict__ xsb, float* __restrict__ hsb) {
  __shared__ float Br_[32][64], Bi_[32][64];  // 16 KB
  int t = blockIdx.x, br = blockIdx.y, ph = blockIdx.z;
  const float* fre = br ? foh_re : fos_re;
  const float* fim = br ? foh_im : fos_im;
  float* outp = br ? hsb : xsb;
  int tid = threadIdx.x;
  int cg_ = tid & 15, pg = tid >> 4;
  float wc[4], ws[4], rc[4], rs[4];
#pragma unroll
  for (int j = 0; j < 4; ++j) {
    int gp = ph * 64 + pg * 4 + j; if (gp > 126) gp = 126;
    __sincosf(CN127F * (float)gp, &rs[j], &rc[j]);
    int r0 = (-63 * gp) % 127;  // k starts at mm=0 -> m=-63 (angle class exact mod 2pi)
    __sincosf(CN127F * (float)r0, &ws[j], &wc[j]);
  }
  float acc[4][4];
#pragma unroll
  for (int j = 0; j < 4; ++j)
#pragma unroll
    for (int q = 0; q < 4; ++q) acc[j][q] = 0.f;
  for (int k0 = 0; k0 < 127; k0 += 32) {
    int kn = (127 - k0 < 32) ? 127 - k0 : 32;
    __syncthreads();
    for (int e = tid; e < 32 * 64; e += 256) {
      int r = e >> 6, j = e & 63;
      if (r < kn) {
        size_t bidx = ((size_t)t * 127 + k0 + r) * 64 + j;
        Br_[r][j] = fre[bidx]; Bi_[r][j] = fim[bidx];
      }
    }
    __syncthreads();
    float4 cbr = *(const float4*)&Br_[0][cg_ * 4];
    float4 cbi = *(const float4*)&Bi_[0][cg_ * 4];
    for (int k = 0; k < kn; ++k) {
      float4 nbr = cbr, nbi = cbi;
      if (k + 1 < kn) {
        nbr = *(const float4*)&Br_[k + 1][cg_ * 4];
        nbi = *(const float4*)&Bi_[k + 1][cg_ * 4];
      }
      float brv[4] = {cbr.x, cbr.y, cbr.z, cbr.w};
      float biv[4] = {cbi.x, cbi.y, cbi.z, cbi.w};
#pragma unroll
      for (int j = 0; j < 4; ++j) {
#pragma unroll
        for (int q = 0; q < 4; ++q) {
          acc[j][q] = fmaf(brv[q], wc[j], acc[j][q]);
          acc[j][q] = fmaf(biv[q], -ws[j], acc[j][q]);
        }
        float nw = wc[j] * rc[j] - ws[j] * rs[j];
        ws[j] = fmaf(wc[j], rs[j], ws[j] * rc[j]);
        wc[j] = nw;
      }
      cbr = nbr; cbi = nbi;
    }
  }
#pragma unroll
  for (int j = 0; j < 4; ++j) {
    int gp = ph * 64 + pg * 4 + j;
    if (gp > 126) continue;
    *(float4*)(outp + ((size_t)t * 127 + gp) * 64 + cg_ * 4) =
        make_float4(acc[j][0], acc[j][1], acc[j][2], acc[j][3]);
  }
}

// ---------------- epilogue: one wave per row ----------------
// grid 2032, block 256 (4 waves).
__global__ __launch_bounds__(256) void ct_fin(const float* __restrict__ xsb,
                                              const float* __restrict__ hsb,
                                              const float* __restrict__ c2w,
                                              const float* __restrict__ c2b,
                                              const float* __restrict__ tv,
                                              const float* __restrict__ lns,
                                              const float* __restrict__ lnb,
                                              float* __restrict__ out) {
  int w = threadIdx.x >> 6, lane = threadIdx.x & 63;
  size_t row = (size_t)blockIdx.x * 4 + w;  // < 8128
  size_t base = row * 64 + lane;
  float hv = hsb[base];
  float xv = xsb[base];
  float acc = c2b[lane] + tv[64 + lane];
#pragma unroll 16
  for (int i = 0; i < 64; ++i)
    acc = fmaf(__shfl(hv, i, 64), c2w[i * 64 + lane], acc);
  float ss = wave_sum64(xv * xv);
  xv = xv / (sqrtf(ss) + 1e-6f);
  float y = xv + acc;
  float g = gelu_tanh(y);
  float mu = wave_sum64(g) * (1.0f / 64.0f);
  float d = g - mu;
  float var = wave_sum64(d * d) * (1.0f / 64.0f);
  out[base] = d * rsqrtf(var + 1e-6f) * lns[lane] + lnb[lane];
}

// ---------------- host launcher ----------------
extern "C" void kernel_launch(void* const* d_in, const int* in_sizes, int n_in,
                              void* d_out, int out_size, void* d_ws, size_t ws_size,
                              hipStream_t stream) {
  const float* x = (const float*)d_in[0];
  const float* temb = (const float*)d_in[1];
  const float* scw = (const float*)d_in[2];
  const float* scb = (const float*)d_in[3];
  const float* swr = (const float*)d_in[4];
  const float* swi = (const float*)d_in[5];
  const float* strw = (const float*)d_in[6];
  const float* strb = (const float*)d_in[7];
  const float* stiw = (const float*)d_in[8];
  const float* stib = (const float*)d_in[9];
  const float* c1w = (const float*)d_in[10];
  const float* c1b = (const float*)d_in[11];
  const float* stw = (const float*)d_in[12];
  const float* stb = (const float*)d_in[13];
  const float* sweight = (const float*)d_in[14];
  const float* c2w = (const float*)d_in[15];
  const float* c2b = (const float*)d_in[16];
  const float* lns = (const float*)d_in[17];
  const float* lnb = (const float*)d_in[18];
  float* out = (float*)d_out;

  char* base = (char*)d_ws;
  size_t off = 0;
  auto alloc = [&](size_t bytes) -> void* {
    void* p = base + off;
    off += (bytes + 255) & ~(size_t)255;
    return p;
  };
  float* tv = (float*)alloc(128 * sizeof(float));
  float* Mm = (float*)alloc(4096 * sizeof(float));
  float* bias2 = (float*)alloc(64 * sizeof(float));
  float2* A2 = (float2*)alloc(262144 * sizeof(float2));
  float* Deff = (float*)alloc(1040384 * sizeof(float));   // [t<128][mm][l]
  float* Dinv = (float*)alloc(520192 * sizeof(float));    // [mm][l][t<64]
  float* ftm_re = (float*)alloc(524288 * sizeof(float));  // [t<128][mi<64][c]
  float* ftm_im = (float*)alloc(524288 * sizeof(float));
  float* flm_re = (float*)alloc(520192 * sizeof(float));  // [mm][l][c]
  float* flm_im = (float*)alloc(520192 * sizeof(float));
  float* s_re = (float*)alloc(520192 * sizeof(float));
  float* s_im = (float*)alloc(520192 * sizeof(float));
  float* h_re = (float*)alloc(520192 * sizeof(float));
  float* h_im = (float*)alloc(520192 * sizeof(float));
  float* fos_re = (float*)alloc(520192 * sizeof(float));  // [t<64][mm][c]
  float* fos_im = (float*)alloc(520192 * sizeof(float));
  float* foh_re = (float*)alloc(520192 * sizeof(float));
  float* foh_im = (float*)alloc(520192 * sizeof(float));
  float* xsb = (float*)alloc(520192 * sizeof(float));
  float* hsb = (float*)alloc(520192 * sizeof(float));
  if (off > ws_size) return;  // workspace too small -> visible failure

  hipLaunchKernelGGL(ct_pre, dim3(640), dim3(256), 0, stream,
                     x, temb, strw, strb, stiw, stib, stw, stb,
                     scw, swr, swi, c1w, c1b, sweight,
                     Deff, Dinv, A2, Mm, bias2, tv, ftm_re, ftm_im);
  hipLaunchKernelGGL(ct_projf, dim3(127, 2), dim3(256), 0, stream, Deff,
                     ftm_re, ftm_im, flm_re, flm_im);
  hipLaunchKernelGGL(ct_mix, dim3(64, 2, 2), dim3(256), 0, stream,
                     flm_re, flm_im, A2, Mm, scb, bias2, Deff,
                     s_re, s_im, h_re, h_im);
  hipLaunchKernelGGL(ct_proji, dim3(127, 2, 2), dim3(256), 0, stream, Dinv,
                     s_re, s_im, h_re, h_im, fos_re, fos_im, foh_re, foh_im);
  hipLaunchKernelGGL(ct_idft, dim3(64, 2, 2), dim3(256), 0, stream,
                     fos_re, fos_im, foh_re, foh_im, xsb, hsb);
  hipLaunchKernelGGL(ct_fin, dim3(2032), dim3(256), 0, stream, xsb, hsb,
                     c2w, c2b, tv, lns, lnb, out);
}